// Round 7
// baseline (307.976 us; speedup 1.0000x reference)
//
#include <hip/hip_runtime.h>
#include <math.h>

#define WW 512
#define HH 512
#define NPIX (WW*HH)
#define NSH 18  /* log2(NPIX) */
#define NXCD 8

typedef unsigned long long u64;
typedef unsigned int u32;
typedef unsigned short u16;

__device__ __forceinline__ u64 umax64(u64 a, u64 b) { return a > b ? a : b; }

// XCD-contiguous block remap for the 1-D kernels (scanpairs/out).
// Grid is always nb*1024 -> divisible by 8, so this is a bijection.
__device__ __forceinline__ int swz_idx() {
  int g = gridDim.x;
  int b = (int)blockIdx.x;
  int nb2 = (b & (NXCD - 1)) * (g >> 3) + (b >> 3);
  return nb2 * 256 + (int)threadIdx.x;
}

// tile mapping for the 2-D kernels: 32x8 tiles, 1024/image, XCD-slab swizzled.
__device__ __forceinline__ void tile_coords(int& bb, int& x0, int& y0) {
  int g = gridDim.x;
  int b = (int)blockIdx.x;
  int t = (b & (NXCD - 1)) * (g >> 3) + (b >> 3);
  bb = t >> 10;
  int rem = t & 1023;
  y0 = (rem >> 4) << 3;   // tile row * 8
  x0 = (rem & 15) << 5;   // tile col * 32
}

// colors + gradient magnitude of pixel p (same __f*_rn sequence as always ->
// bit-identical to the reference's XLA lowering)
__device__ __forceinline__ float d_colg(const float* __restrict__ fb, int p, int pw, int ph,
                                        float col[3]) {
  float s = 0.f;
#pragma unroll
  for (int c = 0; c < 3; ++c) {
    const float* fc = fb + (size_t)c * NPIX;
    float v = fc[p];
    col[c] = v;
    float gx = (pw < WW - 1) ? __fsub_rn(fc[p + 1], v) : 0.f;
    float gy = (ph < HH - 1) ? __fsub_rn(fc[p + WW], v) : 0.f;
    float g = __fsqrt_rn(__fadd_rn(__fadd_rn(__fmul_rn(gx, gx), __fmul_rn(gy, gy)), 1e-12f));
    s = __fadd_rn(s, g);
  }
  return __fdiv_rn(s, 3.0f);
}

// sim bits (<<32) for the undirected edge between means a and b. Bitwise
// symmetric -> ONE exp serves both endpoints; only the tiebreak low word
// (NPIX-lb) is per-side. sim in (0,1] -> bits 62-63 free -> they carry the
// level tag (atomicMax monotone in tag -> no zeroing between levels).
__device__ __forceinline__ u64 d_simbits(float4 a, float4 b) {
  float d0 = __fsub_rn(a.x, b.x);
  float d1 = __fsub_rn(a.y, b.y);
  float d2 = __fsub_rn(a.z, b.z);
  float ss = __fadd_rn(__fadd_rn(__fmul_rn(d0, d0), __fmul_rn(d1, d1)), __fmul_rn(d2, d2));
  float dc = __fsqrt_rn(__fadd_rn(ss, 1e-12f));
  float ge = __fmul_rn(0.5f, __fadd_rn(a.w, b.w));
  float t = __fadd_rn(__fdiv_rn(dc, 10.0f), __fdiv_rn(ge, 27.8f));
  float sim = (float)exp(-(double)t);   // ~correctly-rounded expf
  return ((u64)__float_as_uint(sim)) << 32;
}

// fused prep + level-0 edge pass, tiled (round-3/5 version). Writes level-0
// keys coalesced (tag 0) -- fully initializes the single key buffer, so no
// memset is needed. mcol4[idx] = pixel value = the level-0 MEAN MAP entry.
__global__ __launch_bounds__(256) void k_prep0edge(const float* __restrict__ feat,
                                                   int* __restrict__ labels,
                                                   int* __restrict__ cnt,
                                                   float4* __restrict__ pix4,
                                                   float4* __restrict__ mcol4,
                                                   u64* __restrict__ bnkey) {
  __shared__ float4 scolg[340];   // 34 x 10 halo region
  __shared__ u64 skey[256];
  int bb, x0, y0;
  tile_coords(bb, x0, y0);
  const float* fb = feat + (size_t)bb * 3 * NPIX;
  int tid = (int)threadIdx.x;
  skey[tid] = 0;
  for (int c = tid; c < 340; c += 256) {
    int cx = (c % 34) - 1, cy = (c / 34) - 1;
    int x = x0 + cx, y = y0 + cy;
    if (x >= 0 && x < WW && y >= 0 && y < HH) {
      float col[3];
      float g = d_colg(fb, y * WW + x, x, y, col);
      scolg[c] = make_float4(col[0], col[1], col[2], g);
    }
  }
  __syncthreads();
  int tx = tid & 31, ty = tid >> 5;
  int x = x0 + tx, y = y0 + ty;
  int n = y * WW + x;
  int idx = (bb << NSH) + n;
  int cell = (ty + 1) * 34 + (tx + 1);
  float4 ca = scolg[cell];
  labels[idx] = n;
  cnt[idx] = 1;
  pix4[idx] = ca;
  mcol4[idx] = ca;   // level-0 mean map == pixel (exact: x/1.0)
  u64 key = 0;
  if (x < WW - 1) {              // right edge
    u64 s = d_simbits(ca, scolg[cell + 1]);
    key = umax64(key, s | (u32)(NPIX - (n + 1)));
    if (tx < 31) atomicMax(&skey[tid + 1], s | (u32)(NPIX - n));
  }
  if (tx == 0 && x > 0) {        // left boundary edge (solo)
    u64 s = d_simbits(ca, scolg[cell - 1]);
    key = umax64(key, s | (u32)(NPIX - (n - 1)));
  }
  if (y < HH - 1) {              // down edge
    u64 s = d_simbits(ca, scolg[cell + 34]);
    key = umax64(key, s | (u32)(NPIX - (n + WW)));
    if (ty < 7) atomicMax(&skey[tid + 32], s | (u32)(NPIX - n));
  }
  if (ty == 0 && y > 0) {        // up boundary edge (solo)
    u64 s = d_simbits(ca, scolg[cell - 34]);
    key = umax64(key, s | (u32)(NPIX - (n - WW)));
  }
  __syncthreads();
  bnkey[idx] = umax64(key, skey[tid]);
}

// levels >=1 edge pass. CHANGE (this round's single lever): mcol4 is now a
// per-pixel MEAN MAP (mcol4[idx] = idx's region's current mean, maintained by
// k_scanpairs' member scatter), so the dependent gather chain
// labels[idx]->mcol4[base+la] becomes ONE coalesced read, and tile-boundary
// neighbors are direct labels/mcol4 reads at the neighbor pixel -- no
// indirection anywhere. Everything else is the round-5 structure: right/down
// sims shared via LDS atomics, per-pixel fire-and-forget atomicMax of the
// level-tagged key into the rep's slot of the single key buffer.
__global__ __launch_bounds__(256) void k_edge(const int* __restrict__ labels,
                                              const float4* __restrict__ mcol4,
                                              u64* __restrict__ bnkey, int lvl) {
  __shared__ int sla[256];
  __shared__ float4 sma[256];
  __shared__ u64 skey[256];
  int bb, x0, y0;
  tile_coords(bb, x0, y0);
  int tid = (int)threadIdx.x;
  int tx = tid & 31, ty = tid >> 5;
  int x = x0 + tx, y = y0 + ty;
  int n = y * WW + x;
  int base = bb << NSH;
  int idx = base + n;
  int la = labels[idx];
  float4 ma = mcol4[idx];         // mean map: coalesced, no indirection
  sla[tid] = la;
  sma[tid] = ma;
  skey[tid] = 0;
  __syncthreads();
  u64 key = 0;
  if (x < WW - 1) {              // right edge
    if (tx < 31) {
      int lb = sla[tid + 1];
      if (lb != la) {
        u64 s = d_simbits(ma, sma[tid + 1]);
        key = umax64(key, s | (u32)(NPIX - lb));
        atomicMax(&skey[tid + 1], s | (u32)(NPIX - la));
      }
    } else {
      int lb = labels[idx + 1];
      if (lb != la) key = umax64(key, d_simbits(ma, mcol4[idx + 1]) | (u32)(NPIX - lb));
    }
  }
  if (tx == 0 && x > 0) {        // left boundary edge (solo)
    int lb = labels[idx - 1];
    if (lb != la) key = umax64(key, d_simbits(ma, mcol4[idx - 1]) | (u32)(NPIX - lb));
  }
  if (y < HH - 1) {              // down edge
    if (ty < 7) {
      int lb = sla[tid + 32];
      if (lb != la) {
        u64 s = d_simbits(ma, sma[tid + 32]);
        key = umax64(key, s | (u32)(NPIX - lb));
        atomicMax(&skey[tid + 32], s | (u32)(NPIX - la));
      }
    } else {
      int lb = labels[idx + WW];
      if (lb != la) key = umax64(key, d_simbits(ma, mcol4[idx + WW]) | (u32)(NPIX - lb));
    }
  }
  if (ty == 0 && y > 0) {        // up boundary edge (solo)
    int lb = labels[idx - WW];
    if (lb != la) key = umax64(key, d_simbits(ma, mcol4[idx - WW]) | (u32)(NPIX - lb));
  }
  __syncthreads();
  u64 val = umax64(key, skey[tid]);
  if (val) atomicMax(&bnkey[base + la], ((u64)lvl << 62) | val);
}

// fused scan + pair processing with LDS-level compaction (round-5 version,
// plus the mean-map scatter): the descending merged-list pass now also
// writes the merged mean to EVERY member's mcol4 slot (exclusive writes
// under the perfect matching; identical bits, just replicated) -- this is
// what lets k_edge read means coalesced. LVL0 writes the pair's two slots.
// LAST level keeps the forwarding-marker shortcut (rep slot only; k_out
// gathers via the final label).
template<bool LVL0, bool LAST>
__global__ __launch_bounds__(256) void k_scanpairs(int* __restrict__ labels,
                                                   int* __restrict__ cnt,
                                                   u16* __restrict__ mem,
                                                   const u64* __restrict__ bnkey,
                                                   const float4* __restrict__ pix4,
                                                   float4* __restrict__ mcol4,
                                                   int total, int lvl) {
  __shared__ u64 swl[256];
  __shared__ int scnt;
  if (threadIdx.x == 0) scnt = 0;
  __syncthreads();

  int idx = swz_idx();
  bool pred = false;
  u64 e = 0;
  if (idx < total) {
    int n = idx & (NPIX - 1);
    int base = idx - n;
    u64 K = bnkey[idx];
    bool valid = LVL0 ? true : ((int)(K >> 62) == lvl);   // tag==lvl => live rep
    if (valid) {
      int v = NPIX - (int)(K & 0xffffffffu);
      if (v < NPIX && n < v) {                  // only the min side acts
        u64 Kv = bnkey[base + v];
        bool pv = LVL0 ? true : ((int)(Kv >> 62) == lvl);
        if (pv && NPIX - (int)(Kv & 0xffffffffu) == n) {   // mutual
          pred = true;
          e = ((u64)(u32)idx << 32) | (u32)v;
        }
      }
    }
  }

  u64 mask = __ballot(pred);
  int lane = (int)(threadIdx.x & 63);
  int wb0 = 0;
  if (lane == 0 && mask) wb0 = atomicAdd(&scnt, __popcll(mask));
  int wb = __shfl(wb0, 0);
  if (pred) {
    int pos = wb + __popcll(mask & ((1ull << lane) - 1ull));
    swl[pos] = e;
  }
  __syncthreads();
  int m = scnt;
  if ((int)threadIdx.x >= m) return;

  e = swl[threadIdx.x];
  int idx2 = (int)(e >> 32);
  int v = (int)(e & 0xffffffffu);
  int n = idx2 & (NPIX - 1);
  int base = idx2 - n;
  u16* mo = mem + ((size_t)idx2 << 4);
  if (LVL0) {
    float4 pa = pix4[idx2];
    float4 pb = pix4[base + v];
    float s0 = __fadd_rn(__fadd_rn(0.f, pa.x), pb.x);
    float s1 = __fadd_rn(__fadd_rn(0.f, pa.y), pb.y);
    float s2 = __fadd_rn(__fadd_rn(0.f, pa.z), pb.z);
    float sg = __fadd_rn(__fadd_rn(0.f, pa.w), pb.w);
    mo[0] = 0; mo[1] = (u16)(v - n);
    labels[idx2] = n;
    labels[base + v] = n;
    float4 mean = make_float4(__fdiv_rn(s0, 2.0f), __fdiv_rn(s1, 2.0f),
                              __fdiv_rn(s2, 2.0f), __fdiv_rn(sg, 2.0f));
    mcol4[idx2] = mean;
    mcol4[base + v] = mean;      // mean-map entry for the absorbed pixel
    cnt[idx2] = 2;
    cnt[base + v] = 0;
  } else {
    int c = cnt[idx2];
    int cb = cnt[base + v];
    const u16* ma = mem + ((size_t)idx2 << 4);
    const u16* mb = mem + ((size_t)(base + v) << 4);
    int k = c + cb;
    float s0 = 0.f, s1 = 0.f, s2 = 0.f, sg = 0.f;
    int i = 0, j = 0;
    while (i < c || j < cb) {
      int av = (i < c) ? ((c == 1) ? n : n + (int)ma[i]) : 0x7fffffff;
      int bv = (j < cb) ? ((cb == 1) ? v : v + (int)mb[j]) : 0x7fffffff;
      int x;
      if (av < bv) { x = av; ++i; } else { x = bv; ++j; }
      float4 p = pix4[base + x];
      s0 = __fadd_rn(s0, p.x);
      s1 = __fadd_rn(s1, p.y);
      s2 = __fadd_rn(s2, p.z);
      sg = __fadd_rn(sg, p.w);
      if (!LAST) labels[base + x] = n;
    }
    float safe = (float)k;
    float4 mean = make_float4(__fdiv_rn(s0, safe), __fdiv_rn(s1, safe),
                              __fdiv_rn(s2, safe), __fdiv_rn(sg, safe));
    if (!LAST) {
      // descending in-place merged-list write + mean-map scatter to every
      // member (includes n and v). Write index t2=i2+j2+1 >= i2 and ma[i2]
      // is read before mo[t2] is written -> no unread own-entry clobbered.
      int i2 = c - 1, j2 = cb - 1;
      for (int t2 = k - 1; t2 >= 0; --t2) {
        int av = (i2 >= 0) ? ((c == 1) ? n : n + (int)ma[i2]) : (int)0x80000000;
        int bv = (j2 >= 0) ? ((cb == 1) ? v : v + (int)mb[j2]) : (int)0x80000000;
        int x;
        if (av > bv) { x = av; --i2; } else { x = bv; --j2; }
        mo[t2] = (u16)(x - n);
        mcol4[base + x] = mean;
      }
      cnt[idx2] = k;
      cnt[base + v] = 0;
    } else {
      mcol4[idx2] = mean;        // rep slot only; k_out gathers via label
      cnt[base + v] = -n;        // forwarding marker for k_out
    }
  }
}

// write labels (as f32) + region-mean color map. Resolves the LAST-level
// forwarding marker: cnt[l] <= 0 means l was absorbed at the final level by
// rep -cnt[l].
__global__ __launch_bounds__(256) void k_out(const int* __restrict__ labels,
                                             const int* __restrict__ cnt,
                                             const float4* __restrict__ mcol4,
                                             float* __restrict__ out, int total,
                                             int b0, int Btot) {
  int idx = swz_idx();
  if (idx >= total) return;
  int b = idx >> NSH;
  int n = idx & (NPIX - 1);
  int base = b << NSH;
  int l = labels[idx];
  int c2 = cnt[base + l];
  if (c2 <= 0) l = -c2;
  out[(size_t)(b0 + b) * NPIX + n] = (float)l;
  size_t cb = (size_t)Btot * NPIX;
  float4 m = mcol4[base + l];
  out[cb + ((size_t)(b0 + b) * 3 + 0) * NPIX + n] = m.x;
  out[cb + ((size_t)(b0 + b) * 3 + 1) * NPIX + n] = m.y;
  out[cb + ((size_t)(b0 + b) * 3 + 2) * NPIX + n] = m.z;
}

extern "C" void kernel_launch(void* const* d_in, const int* in_sizes, int n_in,
                              void* d_out, int out_size, void* d_ws, size_t ws_size,
                              hipStream_t stream) {
  const float* feat = (const float*)d_in[0];
  float* out = (float*)d_out;
  int Btot = in_sizes[0] / (3 * NPIX);

  // per-pixel ws bytes:
  //   mcol4 16 + pix4 16 + key 8 + labels 4 + cnt 4 + mem(u16x16) 32 = 80
  const size_t perB = (size_t)NPIX * 80;
  int nbmax = (int)(ws_size / perB);
  if (nbmax < 1) nbmax = 1;
  if (nbmax > Btot) nbmax = Btot;

  for (int b0 = 0; b0 < Btot; b0 += nbmax) {
    int nb = (Btot - b0 < nbmax) ? (Btot - b0) : nbmax;
    size_t cn = (size_t)nb << NSH;
    char* p = (char*)d_ws;
    float4* mcol4 = (float4*)p; p += cn * 16;   // 16B-aligned first
    float4* pix4 = (float4*)p;  p += cn * 16;
    u64* key = (u64*)p;         p += cn * 8;
    int* labels = (int*)p;      p += cn * 4;
    int* cnt = (int*)p;         p += cn * 4;
    u16* mem = (u16*)p;

    const float* fchunk = feat + (size_t)b0 * 3 * NPIX;
    int total = (int)cn;
    int grid = total >> 8;    // nb*1024 blocks, divisible by 8 (swizzle req.)

    k_prep0edge<<<grid, 256, 0, stream>>>(fchunk, labels, cnt, pix4, mcol4, key);
    k_scanpairs<true, false><<<grid, 256, 0, stream>>>(labels, cnt, mem, key,
                                                       pix4, mcol4, total, 0);
    k_edge<<<grid, 256, 0, stream>>>(labels, mcol4, key, 1);
    k_scanpairs<false, false><<<grid, 256, 0, stream>>>(labels, cnt, mem, key,
                                                        pix4, mcol4, total, 1);
    k_edge<<<grid, 256, 0, stream>>>(labels, mcol4, key, 2);
    k_scanpairs<false, false><<<grid, 256, 0, stream>>>(labels, cnt, mem, key,
                                                        pix4, mcol4, total, 2);
    k_edge<<<grid, 256, 0, stream>>>(labels, mcol4, key, 3);
    k_scanpairs<false, true><<<grid, 256, 0, stream>>>(labels, cnt, mem, key,
                                                       pix4, mcol4, total, 3);
    k_out<<<grid, 256, 0, stream>>>(labels, cnt, mcol4, out, total, b0, Btot);
  }
}

// Round 8
// 258.465 us; speedup vs baseline: 1.1916x; 1.1916x over previous
//
#include <hip/hip_runtime.h>
#include <math.h>

#define WW 512
#define HH 512
#define NPIX (WW*HH)
#define NSH 18  /* log2(NPIX) */
#define NXCD 8

typedef unsigned long long u64;
typedef unsigned int u32;
typedef unsigned short u16;

__device__ __forceinline__ u64 umax64(u64 a, u64 b) { return a > b ? a : b; }

// XCD-contiguous block remap for the 1-D kernels (scanpairs/out).
// Grid is always nb*1024 -> divisible by 8, so this is a bijection.
__device__ __forceinline__ int swz_idx() {
  int g = gridDim.x;
  int b = (int)blockIdx.x;
  int nb2 = (b & (NXCD - 1)) * (g >> 3) + (b >> 3);
  return nb2 * 256 + (int)threadIdx.x;
}

// tile mapping for the 2-D kernels: 32x8 tiles, 1024/image, XCD-slab swizzled.
__device__ __forceinline__ void tile_coords(int& bb, int& x0, int& y0) {
  int g = gridDim.x;
  int b = (int)blockIdx.x;
  int t = (b & (NXCD - 1)) * (g >> 3) + (b >> 3);
  bb = t >> 10;
  int rem = t & 1023;
  y0 = (rem >> 4) << 3;   // tile row * 8
  x0 = (rem & 15) << 5;   // tile col * 32
}

// colors + gradient magnitude of pixel p (same __f*_rn sequence as always ->
// bit-identical to the reference's XLA lowering)
__device__ __forceinline__ float d_colg(const float* __restrict__ fb, int p, int pw, int ph,
                                        float col[3]) {
  float s = 0.f;
#pragma unroll
  for (int c = 0; c < 3; ++c) {
    const float* fc = fb + (size_t)c * NPIX;
    float v = fc[p];
    col[c] = v;
    float gx = (pw < WW - 1) ? __fsub_rn(fc[p + 1], v) : 0.f;
    float gy = (ph < HH - 1) ? __fsub_rn(fc[p + WW], v) : 0.f;
    float g = __fsqrt_rn(__fadd_rn(__fadd_rn(__fmul_rn(gx, gx), __fmul_rn(gy, gy)), 1e-12f));
    s = __fadd_rn(s, g);
  }
  return __fdiv_rn(s, 3.0f);
}

// sim bits (<<32) for the undirected edge between means a and b. Bitwise
// symmetric -> ONE exp serves both endpoints; only the tiebreak low word
// (NPIX-lb) is per-side. sim in (0,1] -> bits 62-63 free -> they carry the
// level tag (atomicMax monotone in tag -> no zeroing between levels).
__device__ __forceinline__ u64 d_simbits(float4 a, float4 b) {
  float d0 = __fsub_rn(a.x, b.x);
  float d1 = __fsub_rn(a.y, b.y);
  float d2 = __fsub_rn(a.z, b.z);
  float ss = __fadd_rn(__fadd_rn(__fmul_rn(d0, d0), __fmul_rn(d1, d1)), __fmul_rn(d2, d2));
  float dc = __fsqrt_rn(__fadd_rn(ss, 1e-12f));
  float ge = __fmul_rn(0.5f, __fadd_rn(a.w, b.w));
  float t = __fadd_rn(__fdiv_rn(dc, 10.0f), __fdiv_rn(ge, 27.8f));
  float sim = (float)exp(-(double)t);   // ~correctly-rounded expf
  return ((u64)__float_as_uint(sim)) << 32;
}

// fused prep + level-0 edge pass, tiled (round-5 version, unchanged). Writes
// level-0 keys coalesced (tag 0) -- fully initializes the single key buffer.
__global__ __launch_bounds__(256) void k_prep0edge(const float* __restrict__ feat,
                                                   int* __restrict__ labels,
                                                   int* __restrict__ cnt,
                                                   float4* __restrict__ pix4,
                                                   float4* __restrict__ mcol4,
                                                   u64* __restrict__ bnkey) {
  __shared__ float4 scolg[340];   // 34 x 10 halo region
  __shared__ u64 skey[256];
  int bb, x0, y0;
  tile_coords(bb, x0, y0);
  const float* fb = feat + (size_t)bb * 3 * NPIX;
  int tid = (int)threadIdx.x;
  skey[tid] = 0;
  for (int c = tid; c < 340; c += 256) {
    int cx = (c % 34) - 1, cy = (c / 34) - 1;
    int x = x0 + cx, y = y0 + cy;
    if (x >= 0 && x < WW && y >= 0 && y < HH) {
      float col[3];
      float g = d_colg(fb, y * WW + x, x, y, col);
      scolg[c] = make_float4(col[0], col[1], col[2], g);
    }
  }
  __syncthreads();
  int tx = tid & 31, ty = tid >> 5;
  int x = x0 + tx, y = y0 + ty;
  int n = y * WW + x;
  int idx = (bb << NSH) + n;
  int cell = (ty + 1) * 34 + (tx + 1);
  float4 ca = scolg[cell];
  labels[idx] = n;
  cnt[idx] = 1;
  pix4[idx] = ca;
  mcol4[idx] = ca;   // level-0 region mean == pixel (exact: x/1.0)
  u64 key = 0;
  if (x < WW - 1) {              // right edge
    u64 s = d_simbits(ca, scolg[cell + 1]);
    key = umax64(key, s | (u32)(NPIX - (n + 1)));
    if (tx < 31) atomicMax(&skey[tid + 1], s | (u32)(NPIX - n));
  }
  if (tx == 0 && x > 0) {        // left boundary edge (solo)
    u64 s = d_simbits(ca, scolg[cell - 1]);
    key = umax64(key, s | (u32)(NPIX - (n - 1)));
  }
  if (y < HH - 1) {              // down edge
    u64 s = d_simbits(ca, scolg[cell + 34]);
    key = umax64(key, s | (u32)(NPIX - (n + WW)));
    if (ty < 7) atomicMax(&skey[tid + 32], s | (u32)(NPIX - n));
  }
  if (ty == 0 && y > 0) {        // up boundary edge (solo)
    u64 s = d_simbits(ca, scolg[cell - 34]);
    key = umax64(key, s | (u32)(NPIX - (n - WW)));
  }
  __syncthreads();
  bnkey[idx] = umax64(key, skey[tid]);
}

// levels >=1 edge pass (round-5 structure). CHANGE (this round's lever):
// horizontal RUN-LEADER DEDUP of the global atomics. Regions are spatially
// contiguous, so adjacent pixels in a row usually share la and target the
// same rep slot. After each pixel's final val is known, it is published in
// LDS; the run leader (tx==0 or left label differs) serially maxes over its
// run and issues ONE atomicMax per run instead of one per pixel (~2x fewer
// atomics, less dirty-line writeback). Max over the same set -> identical.
__global__ __launch_bounds__(256) void k_edge(const int* __restrict__ labels,
                                              const float4* __restrict__ mcol4,
                                              u64* __restrict__ bnkey, int lvl) {
  __shared__ int sla[256];
  __shared__ float4 sma[256];
  __shared__ u64 skey[256];
  int bb, x0, y0;
  tile_coords(bb, x0, y0);
  int tid = (int)threadIdx.x;
  int tx = tid & 31, ty = tid >> 5;
  int x = x0 + tx, y = y0 + ty;
  int n = y * WW + x;
  int base = bb << NSH;
  int idx = base + n;
  int la = labels[idx];
  float4 ma = mcol4[base + la];
  sla[tid] = la;
  sma[tid] = ma;
  skey[tid] = 0;
  __syncthreads();
  u64 key = 0;
  if (x < WW - 1) {              // right edge
    if (tx < 31) {
      int lb = sla[tid + 1];
      if (lb != la) {
        u64 s = d_simbits(ma, sma[tid + 1]);
        key = umax64(key, s | (u32)(NPIX - lb));
        atomicMax(&skey[tid + 1], s | (u32)(NPIX - la));
      }
    } else {
      int lb = labels[idx + 1];
      if (lb != la) key = umax64(key, d_simbits(ma, mcol4[base + lb]) | (u32)(NPIX - lb));
    }
  }
  if (tx == 0 && x > 0) {        // left boundary edge (solo)
    int lb = labels[idx - 1];
    if (lb != la) key = umax64(key, d_simbits(ma, mcol4[base + lb]) | (u32)(NPIX - lb));
  }
  if (y < HH - 1) {              // down edge
    if (ty < 7) {
      int lb = sla[tid + 32];
      if (lb != la) {
        u64 s = d_simbits(ma, sma[tid + 32]);
        key = umax64(key, s | (u32)(NPIX - lb));
        atomicMax(&skey[tid + 32], s | (u32)(NPIX - la));
      }
    } else {
      int lb = labels[idx + WW];
      if (lb != la) key = umax64(key, d_simbits(ma, mcol4[base + lb]) | (u32)(NPIX - lb));
    }
  }
  if (ty == 0 && y > 0) {        // up boundary edge (solo)
    int lb = labels[idx - WW];
    if (lb != la) key = umax64(key, d_simbits(ma, mcol4[base + lb]) | (u32)(NPIX - lb));
  }
  __syncthreads();
  // final per-pixel value; each thread reads only its OWN skey slot, so the
  // immediate overwrite below is race-free. One extra barrier publishes all
  // vals for the leader walk.
  u64 val = umax64(key, skey[tid]);
  skey[tid] = val;
  __syncthreads();
  bool leader = (tx == 0) || (sla[tid - 1] != la);
  if (leader) {
    u64 m = val;
    int t = tid + 1, txx = tx + 1;
    while (txx < 32 && sla[t] == la) { m = umax64(m, skey[t]); ++t; ++txx; }
    if (m) atomicMax(&bnkey[base + la], ((u64)lvl << 62) | m);
  }
}

// fused scan + pair processing with LDS-level compaction (round-5 version).
// Micro-change this round: only v-side members are relabeled (rep-side
// members already carry label n -- a region's rep is invariantly its min id,
// and members were labeled n when they joined). Halves the label scatter.
// LAST level writes forwarding markers cnt[absorbed] = -newrep (k_out
// resolves); level 0 skips the redundant labels[idx2]=n (prep wrote identity).
template<bool LVL0, bool LAST>
__global__ __launch_bounds__(256) void k_scanpairs(int* __restrict__ labels,
                                                   int* __restrict__ cnt,
                                                   u16* __restrict__ mem,
                                                   const u64* __restrict__ bnkey,
                                                   const float4* __restrict__ pix4,
                                                   float4* __restrict__ mcol4,
                                                   int total, int lvl) {
  __shared__ u64 swl[256];
  __shared__ int scnt;
  if (threadIdx.x == 0) scnt = 0;
  __syncthreads();

  int idx = swz_idx();
  bool pred = false;
  u64 e = 0;
  if (idx < total) {
    int n = idx & (NPIX - 1);
    int base = idx - n;
    u64 K = bnkey[idx];
    bool valid = LVL0 ? true : ((int)(K >> 62) == lvl);   // tag==lvl => live rep
    if (valid) {
      int v = NPIX - (int)(K & 0xffffffffu);
      if (v < NPIX && n < v) {                  // only the min side acts
        u64 Kv = bnkey[base + v];
        bool pv = LVL0 ? true : ((int)(Kv >> 62) == lvl);
        if (pv && NPIX - (int)(Kv & 0xffffffffu) == n) {   // mutual
          pred = true;
          e = ((u64)(u32)idx << 32) | (u32)v;
        }
      }
    }
  }

  u64 mask = __ballot(pred);
  int lane = (int)(threadIdx.x & 63);
  int wb0 = 0;
  if (lane == 0 && mask) wb0 = atomicAdd(&scnt, __popcll(mask));
  int wb = __shfl(wb0, 0);
  if (pred) {
    int pos = wb + __popcll(mask & ((1ull << lane) - 1ull));
    swl[pos] = e;
  }
  __syncthreads();
  int m = scnt;
  if ((int)threadIdx.x >= m) return;

  e = swl[threadIdx.x];
  int idx2 = (int)(e >> 32);
  int v = (int)(e & 0xffffffffu);
  int n = idx2 & (NPIX - 1);
  int base = idx2 - n;
  u16* mo = mem + ((size_t)idx2 << 4);
  if (LVL0) {
    float4 pa = pix4[idx2];
    float4 pb = pix4[base + v];
    float s0 = __fadd_rn(__fadd_rn(0.f, pa.x), pb.x);
    float s1 = __fadd_rn(__fadd_rn(0.f, pa.y), pb.y);
    float s2 = __fadd_rn(__fadd_rn(0.f, pa.z), pb.z);
    float sg = __fadd_rn(__fadd_rn(0.f, pa.w), pb.w);
    mo[0] = 0; mo[1] = (u16)(v - n);
    labels[base + v] = n;        // rep slot already holds n (prep identity)
    mcol4[idx2] = make_float4(__fdiv_rn(s0, 2.0f), __fdiv_rn(s1, 2.0f),
                              __fdiv_rn(s2, 2.0f), __fdiv_rn(sg, 2.0f));
    cnt[idx2] = 2;
    cnt[base + v] = 0;
  } else {
    int c = cnt[idx2];
    int cb = cnt[base + v];
    const u16* ma = mem + ((size_t)idx2 << 4);
    const u16* mb = mem + ((size_t)(base + v) << 4);
    int k = c + cb;
    float s0 = 0.f, s1 = 0.f, s2 = 0.f, sg = 0.f;
    int i = 0, j = 0;
    while (i < c || j < cb) {
      int av = (i < c) ? ((c == 1) ? n : n + (int)ma[i]) : 0x7fffffff;
      int bv = (j < cb) ? ((cb == 1) ? v : v + (int)mb[j]) : 0x7fffffff;
      int x;
      bool fromB;
      if (av < bv) { x = av; ++i; fromB = false; } else { x = bv; ++j; fromB = true; }
      float4 p = pix4[base + x];
      s0 = __fadd_rn(s0, p.x);
      s1 = __fadd_rn(s1, p.y);
      s2 = __fadd_rn(s2, p.z);
      sg = __fadd_rn(sg, p.w);
      if (!LAST && fromB) labels[base + x] = n;   // rep-side already labeled n
    }
    if (!LAST) {
      // descending in-place merged-list write. Write index t2=i2+j2+1 >= i2
      // and ma[i2] is read before mo[t2] is written -> no unread own-entry
      // clobbered.
      int i2 = c - 1, j2 = cb - 1;
      for (int t2 = k - 1; t2 >= 0; --t2) {
        int av = (i2 >= 0) ? ((c == 1) ? n : n + (int)ma[i2]) : (int)0x80000000;
        int bv = (j2 >= 0) ? ((cb == 1) ? v : v + (int)mb[j2]) : (int)0x80000000;
        int x;
        if (av > bv) { x = av; --i2; } else { x = bv; --j2; }
        mo[t2] = (u16)(x - n);
      }
    }
    float safe = (float)k;
    mcol4[idx2] = make_float4(__fdiv_rn(s0, safe), __fdiv_rn(s1, safe),
                              __fdiv_rn(s2, safe), __fdiv_rn(sg, safe));
    if (LAST) {
      cnt[base + v] = -n;        // forwarding marker for k_out
    } else {
      cnt[idx2] = k;
      cnt[base + v] = 0;
    }
  }
}

// write labels (as f32) + region-mean color map. Resolves the LAST-level
// forwarding marker: cnt[l] <= 0 means l was absorbed at the final level by
// rep -cnt[l].
__global__ __launch_bounds__(256) void k_out(const int* __restrict__ labels,
                                             const int* __restrict__ cnt,
                                             const float4* __restrict__ mcol4,
                                             float* __restrict__ out, int total,
                                             int b0, int Btot) {
  int idx = swz_idx();
  if (idx >= total) return;
  int b = idx >> NSH;
  int n = idx & (NPIX - 1);
  int base = b << NSH;
  int l = labels[idx];
  int c2 = cnt[base + l];
  if (c2 <= 0) l = -c2;
  out[(size_t)(b0 + b) * NPIX + n] = (float)l;
  size_t cb = (size_t)Btot * NPIX;
  float4 m = mcol4[base + l];
  out[cb + ((size_t)(b0 + b) * 3 + 0) * NPIX + n] = m.x;
  out[cb + ((size_t)(b0 + b) * 3 + 1) * NPIX + n] = m.y;
  out[cb + ((size_t)(b0 + b) * 3 + 2) * NPIX + n] = m.z;
}

extern "C" void kernel_launch(void* const* d_in, const int* in_sizes, int n_in,
                              void* d_out, int out_size, void* d_ws, size_t ws_size,
                              hipStream_t stream) {
  const float* feat = (const float*)d_in[0];
  float* out = (float*)d_out;
  int Btot = in_sizes[0] / (3 * NPIX);

  // per-pixel ws bytes:
  //   mcol4 16 + pix4 16 + key 8 + labels 4 + cnt 4 + mem(u16x16) 32 = 80
  const size_t perB = (size_t)NPIX * 80;
  int nbmax = (int)(ws_size / perB);
  if (nbmax < 1) nbmax = 1;
  if (nbmax > Btot) nbmax = Btot;

  for (int b0 = 0; b0 < Btot; b0 += nbmax) {
    int nb = (Btot - b0 < nbmax) ? (Btot - b0) : nbmax;
    size_t cn = (size_t)nb << NSH;
    char* p = (char*)d_ws;
    float4* mcol4 = (float4*)p; p += cn * 16;   // 16B-aligned first
    float4* pix4 = (float4*)p;  p += cn * 16;
    u64* key = (u64*)p;         p += cn * 8;
    int* labels = (int*)p;      p += cn * 4;
    int* cnt = (int*)p;         p += cn * 4;
    u16* mem = (u16*)p;

    const float* fchunk = feat + (size_t)b0 * 3 * NPIX;
    int total = (int)cn;
    int grid = total >> 8;    // nb*1024 blocks, divisible by 8 (swizzle req.)

    k_prep0edge<<<grid, 256, 0, stream>>>(fchunk, labels, cnt, pix4, mcol4, key);
    k_scanpairs<true, false><<<grid, 256, 0, stream>>>(labels, cnt, mem, key,
                                                       pix4, mcol4, total, 0);
    k_edge<<<grid, 256, 0, stream>>>(labels, mcol4, key, 1);
    k_scanpairs<false, false><<<grid, 256, 0, stream>>>(labels, cnt, mem, key,
                                                        pix4, mcol4, total, 1);
    k_edge<<<grid, 256, 0, stream>>>(labels, mcol4, key, 2);
    k_scanpairs<false, false><<<grid, 256, 0, stream>>>(labels, cnt, mem, key,
                                                        pix4, mcol4, total, 2);
    k_edge<<<grid, 256, 0, stream>>>(labels, mcol4, key, 3);
    k_scanpairs<false, true><<<grid, 256, 0, stream>>>(labels, cnt, mem, key,
                                                       pix4, mcol4, total, 3);
    k_out<<<grid, 256, 0, stream>>>(labels, cnt, mcol4, out, total, b0, Btot);
  }
}

// Round 9
// 250.550 us; speedup vs baseline: 1.2292x; 1.0316x over previous
//
#include <hip/hip_runtime.h>
#include <math.h>

#define WW 512
#define HH 512
#define NPIX (WW*HH)
#define NSH 18  /* log2(NPIX) */
#define NXCD 8

typedef unsigned long long u64;
typedef unsigned int u32;
typedef unsigned short u16;

__device__ __forceinline__ u64 umax64(u64 a, u64 b) { return a > b ? a : b; }

// XCD-contiguous block remap for the 1-D kernels (scanpairs/out).
// Grid is always nb*1024 -> divisible by 8, so this is a bijection.
__device__ __forceinline__ int swz_idx() {
  int g = gridDim.x;
  int b = (int)blockIdx.x;
  int nb2 = (b & (NXCD - 1)) * (g >> 3) + (b >> 3);
  return nb2 * 256 + (int)threadIdx.x;
}

// tile mapping for the 2-D kernels: 32x8 tiles, 1024/image, XCD-slab swizzled.
__device__ __forceinline__ void tile_coords(int& bb, int& x0, int& y0) {
  int g = gridDim.x;
  int b = (int)blockIdx.x;
  int t = (b & (NXCD - 1)) * (g >> 3) + (b >> 3);
  bb = t >> 10;
  int rem = t & 1023;
  y0 = (rem >> 4) << 3;   // tile row * 8
  x0 = (rem & 15) << 5;   // tile col * 32
}

// colors + gradient magnitude of pixel p (same __f*_rn sequence as always ->
// bit-identical to the reference's XLA lowering)
__device__ __forceinline__ float d_colg(const float* __restrict__ fb, int p, int pw, int ph,
                                        float col[3]) {
  float s = 0.f;
#pragma unroll
  for (int c = 0; c < 3; ++c) {
    const float* fc = fb + (size_t)c * NPIX;
    float v = fc[p];
    col[c] = v;
    float gx = (pw < WW - 1) ? __fsub_rn(fc[p + 1], v) : 0.f;
    float gy = (ph < HH - 1) ? __fsub_rn(fc[p + WW], v) : 0.f;
    float g = __fsqrt_rn(__fadd_rn(__fadd_rn(__fmul_rn(gx, gx), __fmul_rn(gy, gy)), 1e-12f));
    s = __fadd_rn(s, g);
  }
  return __fdiv_rn(s, 3.0f);
}

// sim bits (<<32) for the undirected edge between means a and b. Bitwise
// symmetric -> ONE exp serves both endpoints; only the tiebreak low word
// (NPIX-lb) is per-side. sim in (0,1] -> bits 62-63 free -> they carry the
// level tag (atomicMax monotone in tag -> no zeroing between levels).
__device__ __forceinline__ u64 d_simbits(float4 a, float4 b) {
  float d0 = __fsub_rn(a.x, b.x);
  float d1 = __fsub_rn(a.y, b.y);
  float d2 = __fsub_rn(a.z, b.z);
  float ss = __fadd_rn(__fadd_rn(__fmul_rn(d0, d0), __fmul_rn(d1, d1)), __fmul_rn(d2, d2));
  float dc = __fsqrt_rn(__fadd_rn(ss, 1e-12f));
  float ge = __fmul_rn(0.5f, __fadd_rn(a.w, b.w));
  float t = __fadd_rn(__fdiv_rn(dc, 10.0f), __fdiv_rn(ge, 27.8f));
  float sim = (float)exp(-(double)t);   // ~correctly-rounded expf
  return ((u64)__float_as_uint(sim)) << 32;
}

// FUSED prep + level-0 edge + level-0 scan/merge (round-6 kernel, harness-
// verified; this round's single change is re-adopting it next to the
// round-8 k_edge). Level 0 is a pure function of feat, so BOTH sides of a
// pair compute the same mutual decision independently (bit-identical: same
// colg inputs, same sim sequences, max is order-independent) and each writes
// only ITS OWN slot -> no cross-tile writes, no races, and the 47 us sp0
// dispatch is deleted.
//   halo: colg on 36x12 (partner v is 1 off-tile; v's edges reach 2).
//   phase A: own-key build, right/down sims shared via LDS atomics; the
//            final key is ALSO written to bnkey[idx] (tag 0, coalesced) --
//            this (re)initializes the single key buffer each chunk, which
//            the tag scheme requires (stale tag-1..3 entries from a previous
//            chunk/replay would alias sp's tag check). Replaces a memset at
//            identical byte cost.
//   phase B: publish full keys in LDS; decode v; key(v) = LDS if in-tile,
//            else solo recompute from halo; mutual test; per-slot writes:
//            rep (n<v): labels=n cnt=2 mcol4=mean mem={0,v-n}
//            absorbed : labels=v cnt=0 mcol4=pix
//            unpaired : labels=n cnt=1 mcol4=pix
__global__ __launch_bounds__(256) void k_prep0(const float* __restrict__ feat,
                                               int* __restrict__ labels,
                                               int* __restrict__ cnt,
                                               float4* __restrict__ pix4,
                                               float4* __restrict__ mcol4,
                                               u16* __restrict__ mem,
                                               u64* __restrict__ bnkey) {
  __shared__ float4 scolg[432];   // 36 x 12: cx in [-2,33], cy in [-2,9]
  __shared__ u64 skey[256];
  int bb, x0, y0;
  tile_coords(bb, x0, y0);
  const float* fb = feat + (size_t)bb * 3 * NPIX;
  int tid = (int)threadIdx.x;
  skey[tid] = 0;
  for (int c = tid; c < 432; c += 256) {
    int cx = (c % 36) - 2, cy = (c / 36) - 2;
    int x = x0 + cx, y = y0 + cy;
    if (x >= 0 && x < WW && y >= 0 && y < HH) {
      float col[3];
      float g = d_colg(fb, y * WW + x, x, y, col);
      scolg[c] = make_float4(col[0], col[1], col[2], g);
    }
  }
  __syncthreads();
  int tx = tid & 31, ty = tid >> 5;
  int x = x0 + tx, y = y0 + ty;
  int n = y * WW + x;
  int idx = (bb << NSH) + n;
  int cc = (ty + 2) * 36 + (tx + 2);
  float4 ca = scolg[cc];
  pix4[idx] = ca;
  u64 key = 0;
  if (x < WW - 1) {              // right edge (shared in-tile)
    u64 s = d_simbits(ca, scolg[cc + 1]);
    key = umax64(key, s | (u32)(NPIX - (n + 1)));
    if (tx < 31) atomicMax(&skey[tid + 1], s | (u32)(NPIX - n));
  }
  if (tx == 0 && x > 0)          // left boundary edge (solo)
    key = umax64(key, d_simbits(ca, scolg[cc - 1]) | (u32)(NPIX - (n - 1)));
  if (y < HH - 1) {              // down edge (shared in-tile)
    u64 s = d_simbits(ca, scolg[cc + 36]);
    key = umax64(key, s | (u32)(NPIX - (n + WW)));
    if (ty < 7) atomicMax(&skey[tid + 32], s | (u32)(NPIX - n));
  }
  if (ty == 0 && y > 0)          // up boundary edge (solo)
    key = umax64(key, d_simbits(ca, scolg[cc - 36]) | (u32)(NPIX - (n - WW)));
  __syncthreads();
  key = umax64(key, skey[tid]);  // own-slot read/write only -> no hazard
  bnkey[idx] = key;              // tag-0 init of the single key buffer
  skey[tid] = key;               // publish full key for in-tile lookups
  __syncthreads();

  int v = NPIX - (int)(key & 0xffffffffu);   // every pixel has >=2 edges -> valid
  int vx = v & (WW - 1), vy = v >> 9;
  u64 kv;
  if (vx >= x0 && vx < x0 + 32 && vy >= y0 && vy < y0 + 8) {
    kv = skey[(vy - y0) * 32 + (vx - x0)];
  } else {
    int vc = (vy - y0 + 2) * 36 + (vx - x0 + 2);
    float4 cv = scolg[vc];
    kv = 0;
    if (vx < WW - 1) kv = umax64(kv, d_simbits(cv, scolg[vc + 1]) | (u32)(NPIX - (v + 1)));
    if (vx > 0)      kv = umax64(kv, d_simbits(cv, scolg[vc - 1]) | (u32)(NPIX - (v - 1)));
    if (vy < HH - 1) kv = umax64(kv, d_simbits(cv, scolg[vc + 36]) | (u32)(NPIX - (v + WW)));
    if (vy > 0)      kv = umax64(kv, d_simbits(cv, scolg[vc - 36]) | (u32)(NPIX - (v - WW)));
  }
  bool mutual = (NPIX - (int)(kv & 0xffffffffu)) == n;
  if (mutual) {
    if (n < v) {   // rep side: ascending-order mean (n then v), exact sequence
      float4 pb = scolg[(vy - y0 + 2) * 36 + (vx - x0 + 2)];
      float s0 = __fadd_rn(__fadd_rn(0.f, ca.x), pb.x);
      float s1 = __fadd_rn(__fadd_rn(0.f, ca.y), pb.y);
      float s2 = __fadd_rn(__fadd_rn(0.f, ca.z), pb.z);
      float sg = __fadd_rn(__fadd_rn(0.f, ca.w), pb.w);
      mcol4[idx] = make_float4(__fdiv_rn(s0, 2.0f), __fdiv_rn(s1, 2.0f),
                               __fdiv_rn(s2, 2.0f), __fdiv_rn(sg, 2.0f));
      labels[idx] = n;
      cnt[idx] = 2;
      u16* mo = mem + ((size_t)idx << 4);
      mo[0] = 0; mo[1] = (u16)(v - n);
    } else {       // absorbed side
      labels[idx] = v;
      cnt[idx] = 0;
      mcol4[idx] = ca;
    }
  } else {
    labels[idx] = n;
    cnt[idx] = 1;
    mcol4[idx] = ca;
  }
}

// levels >=1 edge pass (round-8 version, unchanged): 32x8 tile, mean gather
// via labels, right/down sims shared via LDS atomics, horizontal RUN-LEADER
// DEDUP of the global atomics (one atomicMax per same-label run instead of
// one per pixel). Max over the same set -> bit-identical.
__global__ __launch_bounds__(256) void k_edge(const int* __restrict__ labels,
                                              const float4* __restrict__ mcol4,
                                              u64* __restrict__ bnkey, int lvl) {
  __shared__ int sla[256];
  __shared__ float4 sma[256];
  __shared__ u64 skey[256];
  int bb, x0, y0;
  tile_coords(bb, x0, y0);
  int tid = (int)threadIdx.x;
  int tx = tid & 31, ty = tid >> 5;
  int x = x0 + tx, y = y0 + ty;
  int n = y * WW + x;
  int base = bb << NSH;
  int idx = base + n;
  int la = labels[idx];
  float4 ma = mcol4[base + la];
  sla[tid] = la;
  sma[tid] = ma;
  skey[tid] = 0;
  __syncthreads();
  u64 key = 0;
  if (x < WW - 1) {              // right edge
    if (tx < 31) {
      int lb = sla[tid + 1];
      if (lb != la) {
        u64 s = d_simbits(ma, sma[tid + 1]);
        key = umax64(key, s | (u32)(NPIX - lb));
        atomicMax(&skey[tid + 1], s | (u32)(NPIX - la));
      }
    } else {
      int lb = labels[idx + 1];
      if (lb != la) key = umax64(key, d_simbits(ma, mcol4[base + lb]) | (u32)(NPIX - lb));
    }
  }
  if (tx == 0 && x > 0) {        // left boundary edge (solo)
    int lb = labels[idx - 1];
    if (lb != la) key = umax64(key, d_simbits(ma, mcol4[base + lb]) | (u32)(NPIX - lb));
  }
  if (y < HH - 1) {              // down edge
    if (ty < 7) {
      int lb = sla[tid + 32];
      if (lb != la) {
        u64 s = d_simbits(ma, sma[tid + 32]);
        key = umax64(key, s | (u32)(NPIX - lb));
        atomicMax(&skey[tid + 32], s | (u32)(NPIX - la));
      }
    } else {
      int lb = labels[idx + WW];
      if (lb != la) key = umax64(key, d_simbits(ma, mcol4[base + lb]) | (u32)(NPIX - lb));
    }
  }
  if (ty == 0 && y > 0) {        // up boundary edge (solo)
    int lb = labels[idx - WW];
    if (lb != la) key = umax64(key, d_simbits(ma, mcol4[base + lb]) | (u32)(NPIX - lb));
  }
  __syncthreads();
  // final per-pixel value; each thread reads only its OWN skey slot, so the
  // immediate overwrite below is race-free. One extra barrier publishes all
  // vals for the leader walk.
  u64 val = umax64(key, skey[tid]);
  skey[tid] = val;
  __syncthreads();
  bool leader = (tx == 0) || (sla[tid - 1] != la);
  if (leader) {
    u64 m = val;
    int t = tid + 1, txx = tx + 1;
    while (txx < 32 && sla[t] == la) { m = umax64(m, skey[t]); ++t; ++txx; }
    if (m) atomicMax(&bnkey[base + la], ((u64)lvl << 62) | m);
  }
}

// fused scan + pair processing with LDS-level compaction, levels 1-3
// (round-8 version; the LVL0 instantiation is gone -- level 0 merges in
// k_prep0). Only v-side members are relabeled (rep-side members already
// carry label n: a region's rep is invariantly its min id). LAST level
// writes forwarding markers cnt[absorbed] = -newrep (k_out resolves).
template<bool LAST>
__global__ __launch_bounds__(256) void k_scanpairs(int* __restrict__ labels,
                                                   int* __restrict__ cnt,
                                                   u16* __restrict__ mem,
                                                   const u64* __restrict__ bnkey,
                                                   const float4* __restrict__ pix4,
                                                   float4* __restrict__ mcol4,
                                                   int total, int lvl) {
  __shared__ u64 swl[256];
  __shared__ int scnt;
  if (threadIdx.x == 0) scnt = 0;
  __syncthreads();

  int idx = swz_idx();
  bool pred = false;
  u64 e = 0;
  if (idx < total) {
    int n = idx & (NPIX - 1);
    int base = idx - n;
    u64 K = bnkey[idx];
    if ((int)(K >> 62) == lvl) {             // tag==lvl => live rep
      int v = NPIX - (int)(K & 0xffffffffu);
      if (v < NPIX && n < v) {               // only the min side acts
        u64 Kv = bnkey[base + v];
        if ((int)(Kv >> 62) == lvl && NPIX - (int)(Kv & 0xffffffffu) == n) {
          pred = true;
          e = ((u64)(u32)idx << 32) | (u32)v;
        }
      }
    }
  }

  u64 mask = __ballot(pred);
  int lane = (int)(threadIdx.x & 63);
  int wb0 = 0;
  if (lane == 0 && mask) wb0 = atomicAdd(&scnt, __popcll(mask));
  int wb = __shfl(wb0, 0);
  if (pred) {
    int pos = wb + __popcll(mask & ((1ull << lane) - 1ull));
    swl[pos] = e;
  }
  __syncthreads();
  int m = scnt;
  if ((int)threadIdx.x >= m) return;

  e = swl[threadIdx.x];
  int idx2 = (int)(e >> 32);
  int v = (int)(e & 0xffffffffu);
  int n = idx2 & (NPIX - 1);
  int base = idx2 - n;
  u16* mo = mem + ((size_t)idx2 << 4);
  int c = cnt[idx2];
  int cb = cnt[base + v];
  const u16* ma = mem + ((size_t)idx2 << 4);
  const u16* mb = mem + ((size_t)(base + v) << 4);
  int k = c + cb;
  float s0 = 0.f, s1 = 0.f, s2 = 0.f, sg = 0.f;
  int i = 0, j = 0;
  while (i < c || j < cb) {
    int av = (i < c) ? ((c == 1) ? n : n + (int)ma[i]) : 0x7fffffff;
    int bv = (j < cb) ? ((cb == 1) ? v : v + (int)mb[j]) : 0x7fffffff;
    int x;
    bool fromB;
    if (av < bv) { x = av; ++i; fromB = false; } else { x = bv; ++j; fromB = true; }
    float4 p = pix4[base + x];
    s0 = __fadd_rn(s0, p.x);
    s1 = __fadd_rn(s1, p.y);
    s2 = __fadd_rn(s2, p.z);
    sg = __fadd_rn(sg, p.w);
    if (!LAST && fromB) labels[base + x] = n;   // rep-side already labeled n
  }
  if (!LAST) {
    // descending in-place merged-list write. Write index t2=i2+j2+1 >= i2
    // and ma[i2] is read before mo[t2] is written -> no unread own-entry
    // clobbered.
    int i2 = c - 1, j2 = cb - 1;
    for (int t2 = k - 1; t2 >= 0; --t2) {
      int av = (i2 >= 0) ? ((c == 1) ? n : n + (int)ma[i2]) : (int)0x80000000;
      int bv = (j2 >= 0) ? ((cb == 1) ? v : v + (int)mb[j2]) : (int)0x80000000;
      int x;
      if (av > bv) { x = av; --i2; } else { x = bv; --j2; }
      mo[t2] = (u16)(x - n);
    }
  }
  float safe = (float)k;
  mcol4[idx2] = make_float4(__fdiv_rn(s0, safe), __fdiv_rn(s1, safe),
                            __fdiv_rn(s2, safe), __fdiv_rn(sg, safe));
  if (LAST) {
    cnt[base + v] = -n;          // forwarding marker for k_out
  } else {
    cnt[idx2] = k;
    cnt[base + v] = 0;
  }
}

// write labels (as f32) + region-mean color map. Resolves the LAST-level
// forwarding marker: cnt[l] <= 0 means l was absorbed at the final level by
// rep -cnt[l].
__global__ __launch_bounds__(256) void k_out(const int* __restrict__ labels,
                                             const int* __restrict__ cnt,
                                             const float4* __restrict__ mcol4,
                                             float* __restrict__ out, int total,
                                             int b0, int Btot) {
  int idx = swz_idx();
  if (idx >= total) return;
  int b = idx >> NSH;
  int n = idx & (NPIX - 1);
  int base = b << NSH;
  int l = labels[idx];
  int c2 = cnt[base + l];
  if (c2 <= 0) l = -c2;
  out[(size_t)(b0 + b) * NPIX + n] = (float)l;
  size_t cb = (size_t)Btot * NPIX;
  float4 m = mcol4[base + l];
  out[cb + ((size_t)(b0 + b) * 3 + 0) * NPIX + n] = m.x;
  out[cb + ((size_t)(b0 + b) * 3 + 1) * NPIX + n] = m.y;
  out[cb + ((size_t)(b0 + b) * 3 + 2) * NPIX + n] = m.z;
}

extern "C" void kernel_launch(void* const* d_in, const int* in_sizes, int n_in,
                              void* d_out, int out_size, void* d_ws, size_t ws_size,
                              hipStream_t stream) {
  const float* feat = (const float*)d_in[0];
  float* out = (float*)d_out;
  int Btot = in_sizes[0] / (3 * NPIX);

  // per-pixel ws bytes:
  //   mcol4 16 + pix4 16 + key 8 + labels 4 + cnt 4 + mem(u16x16) 32 = 80
  const size_t perB = (size_t)NPIX * 80;
  int nbmax = (int)(ws_size / perB);
  if (nbmax < 1) nbmax = 1;
  if (nbmax > Btot) nbmax = Btot;

  for (int b0 = 0; b0 < Btot; b0 += nbmax) {
    int nb = (Btot - b0 < nbmax) ? (Btot - b0) : nbmax;
    size_t cn = (size_t)nb << NSH;
    char* p = (char*)d_ws;
    float4* mcol4 = (float4*)p; p += cn * 16;   // 16B-aligned first
    float4* pix4 = (float4*)p;  p += cn * 16;
    u64* key = (u64*)p;         p += cn * 8;
    int* labels = (int*)p;      p += cn * 4;
    int* cnt = (int*)p;         p += cn * 4;
    u16* mem = (u16*)p;

    const float* fchunk = feat + (size_t)b0 * 3 * NPIX;
    int total = (int)cn;
    int grid = total >> 8;    // nb*1024 blocks, divisible by 8 (swizzle req.)

    k_prep0<<<grid, 256, 0, stream>>>(fchunk, labels, cnt, pix4, mcol4, mem, key);
    k_edge<<<grid, 256, 0, stream>>>(labels, mcol4, key, 1);
    k_scanpairs<false><<<grid, 256, 0, stream>>>(labels, cnt, mem, key,
                                                 pix4, mcol4, total, 1);
    k_edge<<<grid, 256, 0, stream>>>(labels, mcol4, key, 2);
    k_scanpairs<false><<<grid, 256, 0, stream>>>(labels, cnt, mem, key,
                                                 pix4, mcol4, total, 2);
    k_edge<<<grid, 256, 0, stream>>>(labels, mcol4, key, 3);
    k_scanpairs<true><<<grid, 256, 0, stream>>>(labels, cnt, mem, key,
                                                pix4, mcol4, total, 3);
    k_out<<<grid, 256, 0, stream>>>(labels, cnt, mcol4, out, total, b0, Btot);
  }
}